// Round 17
// baseline (70.189 us; speedup 1.0000x reference)
//
#include <hip/hip_runtime.h>

// GraphConv2d (EdgeConv): out[b,o,n] = max_k relu( W·[x_n, x_m-x_n] + b )
// Factorized: U[b,n,o] = (W1-W2)·x_n + b ; V[b,m,o] = W2·x_m
//             out = relu(U + max_k V[m_k])   (relu monotone, U k-invariant)
// B=2, C=64, N=65536, K=16, OUT=64.
// r16: V int8 (64B row = 1 L2 line = 1 request/edge, 2M total). 50.6us.
// r17: k2 de-phased -- no output LDS tile: 8 lanes/node (dwordx2 gather,
// direct 32B nt out segments), LDS 4.2KB, (256,8) = 32 waves/CU. Gathers
// stay in flight until block end; stream phases overlap across 8 blocks/CU.

using u32 = unsigned int;
using u16 = unsigned short;
using u8 = unsigned char;
typedef short short8 __attribute__((ext_vector_type(8)));
typedef float f32x4 __attribute__((ext_vector_type(4)));
typedef int i32x4 __attribute__((ext_vector_type(4)));
typedef u32 u32x4 __attribute__((ext_vector_type(4)));
typedef u32 u32x2 __attribute__((ext_vector_type(2)));

#define NN 65536
#define VSCL 15.875f        // 127/8
#define VDEQ 0.0629921260f  // 8/127

static __device__ __forceinline__ u16 bf16r(float a) {
  u32 u = __builtin_bit_cast(u32, a);
  return (u16)((u + 0x7fffu + ((u >> 16) & 1u)) >> 16);  // RNE
}
static __device__ __forceinline__ u32 pack_bf16(float a, float b) {
  return (u32)bf16r(a) | ((u32)bf16r(b) << 16);
}
static __device__ __forceinline__ float bflo(u32 x) {
  return __builtin_bit_cast(float, x << 16);
}
static __device__ __forceinline__ float bfhi(u32 x) {
  return __builtin_bit_cast(float, x & 0xffff0000u);
}

// ---- kernel 0: Wcat[128][64] bf16: rows 0..63 = (W1-W2), 64..127 = W2 ----
__global__ __launch_bounds__(256) void prep_w(const float* __restrict__ W,
                                              u32* __restrict__ Wcat) {
  int id = blockIdx.x * 256 + threadIdx.x;  // 0..4095 (grid=16)
  int o = id >> 5, c2 = id & 31;
  float f0, f1;
  if (o < 64) {
    f0 = W[o * 128 + 2 * c2]     - W[o * 128 + 64 + 2 * c2];
    f1 = W[o * 128 + 2 * c2 + 1] - W[o * 128 + 64 + 2 * c2 + 1];
  } else {
    int om = o - 64;
    f0 = W[om * 128 + 64 + 2 * c2];
    f1 = W[om * 128 + 64 + 2 * c2 + 1];
  }
  Wcat[id] = pack_bf16(f0, f1);
}

// ---- kernel 1: U (bf16 128B rows), V8 (u8 64B rows) via MFMA GEMM ----
// A = x tile [64 nodes][64 ch] bf16 (LDS) ; B^T = Wcat [128 outs][64 ch] (LDS)
__global__ __launch_bounds__(256, 6) void k1(const float* __restrict__ x,
                                             const float* __restrict__ bias,
                                             const u32* __restrict__ Wcat,
                                             u32* __restrict__ Up,
                                             u32* __restrict__ V8p) {
  __shared__ __align__(16) char smem[26880];  // Wb(18432)+Xa(8448); TR(12800)
  u32* Wb = (u32*)smem;            // [128][36] u32  (row = 72 bf16, padded)
  u32* Xa = (u32*)(smem + 18432);  // [64][33] u32   (row = 66 bf16, padded)

  int t = threadIdx.x;
  int l = t & 63;   // lane
  int w = t >> 6;   // wave 0..3
  int b = blockIdx.x >> 10;
  int n0 = (blockIdx.x & 1023) << 6;

  // stage Wcat -> LDS (padded rows, conflict-free b128 reads later)
#pragma unroll
  for (int i = 0; i < 16; ++i) {
    int id = i * 256 + t;  // o = id>>5, c2 = id&31
    Wb[(id >> 5) * 36 + (id & 31)] = Wcat[id];
  }
  // stage x tile -> LDS bf16 pairs: Xa[node][ch], coalesced 256B reads
#pragma unroll
  for (int r = 0; r < 8; ++r) {
    int c2 = r * 4 + w;
    size_t base = ((size_t)(b * 64 + 2 * c2)) * NN + n0 + l;
    Xa[l * 33 + c2] = pack_bf16(x[base], x[base + NN]);
  }
  __syncthreads();

  f32x4 acc[8];
#pragma unroll
  for (int f = 0; f < 8; ++f) acc[f] = {0.f, 0.f, 0.f, 0.f};

  // wave w owns nodes 16w..16w+15 (C rows), all 128 outs (8 col-frags)
#pragma unroll
  for (int kb = 0; kb < 2; ++kb) {  // K = 64 = 2 x 32
    int ar = (16 * w + (l & 15)) * 33 + kb * 16 + 4 * (l >> 4);
    i32x4 av = {(int)Xa[ar], (int)Xa[ar + 1], (int)Xa[ar + 2], (int)Xa[ar + 3]};
    short8 a = __builtin_bit_cast(short8, av);
#pragma unroll
    for (int f = 0; f < 8; ++f) {
      i32x4 bv = *(const i32x4*)(Wb + (16 * f + (l & 15)) * 36 + kb * 16 + 4 * (l >> 4));
      short8 bb = __builtin_bit_cast(short8, bv);
      acc[f] = __builtin_amdgcn_mfma_f32_16x16x32_bf16(a, bb, acc[f], 0, 0, 0);
    }
  }

  float bs[4];
#pragma unroll
  for (int f = 0; f < 4; ++f) bs[f] = bias[16 * f + (l & 15)];

  __syncthreads();  // all waves done with Wb/Xa before TR reuse
  u16* TRU16 = (u16*)smem;            // [64 nodes][66 u16]: U row (64 bf16 + pad)
  u8* TRV8 = (u8*)(smem + 8448);      // [64 nodes][68 u8]:  V row (64 u8 + pad)
#pragma unroll
  for (int f = 0; f < 4; ++f) {
#pragma unroll
    for (int r = 0; r < 4; ++r) {
      int node = 16 * w + 4 * (l >> 4) + r;  // D row = (lane>>4)*4 + reg
      int o = 16 * f + (l & 15);             // D col = lane&15
      float uval = acc[f][r] + bs[f];        // Wcat rows 0..63 already (W1-W2)
      float vval = acc[f + 4][r];
      TRU16[node * 66 + o] = bf16r(uval);
      float q = fminf(fmaxf(vval * VSCL, -127.f), 127.f);
      TRV8[node * 68 + o] = (u8)((int)rintf(q) + 128);
    }
  }
  __syncthreads();

  // coalesced writeback: U 2048 u32 (8 iters), V8 1024 u32 (4 iters)
  u32* TRU32 = (u32*)smem;
  u32* TRV32 = (u32*)(smem + 8448);
#pragma unroll
  for (int i = 0; i < 8; ++i) {
    int id = i * 256 + t;  // node = id>>5, c = id&31
    int node = id >> 5, c = id & 31;
    Up[((size_t)b * NN + n0 + node) * 32 + c] = TRU32[node * 33 + c];
  }
#pragma unroll
  for (int i = 0; i < 4; ++i) {
    int id = i * 256 + t;  // node = id>>4, c = id&15
    int node = id >> 4, c = id & 15;
    V8p[((size_t)b * NN + n0 + node) * 16 + c] = TRV32[node * 17 + c];
  }
}

// ---- kernel 2: gather + max + relu; no output tile, direct nt stores ----
// slot = bx&7 (XCD): b = slot&1, quad = slot>>1; per-XCD table = 4.0MB.
// 8 lanes/node (ns = l&7 node-sub, c8 = l>>3 channel-group): dwordx2 gather
// (8 lanes cover one 64B row = 1 line/edge); out = 32B nt segments.
__global__ __launch_bounds__(256, 8) void k2(const int* __restrict__ eidx,
                                             const u32* __restrict__ Up,
                                             const u32* __restrict__ V8p,
                                             float* __restrict__ out) {
  __shared__ __align__(16) int eixT[16 * 65];  // [e][node] idx, transposed

  int t = threadIdx.x;
  int bx = blockIdx.x;
  int slot = bx & 7;
  int b = slot & 1;
  int quad = slot >> 1;
  int n0 = ((bx >> 3) + (quad << 8)) << 6;

  // stage + transpose this tile's 1024 indices (nt: don't evict V8 from L2)
  {
    i32x4 v = __builtin_nontemporal_load(
        (const i32x4*)(eidx + ((size_t)b * NN + n0) * 16) + t);
    int node = t >> 2, e0 = (t & 3) * 4;
    eixT[(e0 + 0) * 65 + node] = v.x;
    eixT[(e0 + 1) * 65 + node] = v.y;
    eixT[(e0 + 2) * 65 + node] = v.z;
    eixT[(e0 + 3) * 65 + node] = v.w;
  }
  __syncthreads();

  int l = t & 63, w = t >> 6;
  int ns = l & 7;   // node-sub 0..7 (consecutive lanes = consecutive nodes)
  int c8 = l >> 3;  // channel group: channels c8*8 .. c8*8+7

  const u32* Vb = V8p + ((size_t)b * NN) * 16 + c8 * 2;

#pragma unroll
  for (int pass = 0; pass < 2; ++pass) {
    int node = w * 16 + pass * 8 + ns;

    float mx[8];  // biased-byte domain
#pragma unroll
    for (int i = 0; i < 8; ++i) mx[i] = 0.f;

#pragma unroll
    for (int hb = 0; hb < 4; ++hb) {
      u32x2 vr[4];
#pragma unroll
      for (int e = 0; e < 4; ++e) {
        int id = eixT[(hb * 4 + e) * 65 + node];  // 8-way LDS broadcast
        vr[e] = *(const u32x2*)(Vb + (size_t)id * 16);  // 8B of 64B row
      }
#pragma unroll
      for (int e = 0; e < 4; ++e) {
#pragma unroll
        for (int d = 0; d < 2; ++d) {
          u32 dw = vr[e][d];
          mx[4 * d + 0] = fmaxf(mx[4 * d + 0], (float)(dw & 0xffu));
          mx[4 * d + 1] = fmaxf(mx[4 * d + 1], (float)((dw >> 8) & 0xffu));
          mx[4 * d + 2] = fmaxf(mx[4 * d + 2], (float)((dw >> 16) & 0xffu));
          mx[4 * d + 3] = fmaxf(mx[4 * d + 3], (float)((dw >> 24) & 0xffu));
        }
      }
    }

    // U slice: 8 channels = 4 u32 (bf16 pairs) at c8*4 of the 32-u32 row
    u32x4 uv = __builtin_nontemporal_load(
        (const u32x4*)(Up + ((size_t)b * NN + n0 + node) * 32 + c8 * 4));
    float* ob = out + ((size_t)(b * 64 + c8 * 8)) * NN + n0 + node;
#pragma unroll
    for (int j = 0; j < 4; ++j) {
      u32 uw = uv[j];
      __builtin_nontemporal_store(
          fmaxf(bflo(uw) + (mx[2 * j] - 128.f) * VDEQ, 0.f),
          ob + (size_t)(2 * j) * NN);
      __builtin_nontemporal_store(
          fmaxf(bfhi(uw) + (mx[2 * j + 1] - 128.f) * VDEQ, 0.f),
          ob + (size_t)(2 * j + 1) * NN);
    }
  }
}

extern "C" void kernel_launch(void* const* d_in, const int* in_sizes, int n_in,
                              void* d_out, int out_size, void* d_ws, size_t ws_size,
                              hipStream_t stream) {
  const float* x = (const float*)d_in[0];
  const int* eidx = (const int*)d_in[1];
  const float* W = (const float*)d_in[2];
  const float* bias = (const float*)d_in[3];

  // ws: U (16 MB, 2 x N x 32 u32) | V8 (8 MB, 2 x N x 16 u32) | Wcat (16 KB)
  u32* Up = (u32*)d_ws;
  u32* V8p = Up + (size_t)2 * NN * 32;
  u32* Wcat = (u32*)((char*)d_ws + (size_t)24 * 1024 * 1024);

  prep_w<<<16, 256, 0, stream>>>(W, Wcat);
  k1<<<2 * 1024, 256, 0, stream>>>(x, bias, Wcat, Up, V8p);
  k2<<<2 * 1024, 256, 0, stream>>>(eidx, Up, V8p, (float*)d_out);
}

// Round 18
// 54.776 us; speedup vs baseline: 1.2814x; 1.2814x over previous
//
#include <hip/hip_runtime.h>

// GraphConv2d (EdgeConv): out[b,o,n] = max_k relu( W·[x_n, x_m-x_n] + b )
// Factorized: U[b,n,o] = (W1-W2)·x_n + b ; V[b,m,o] = W2·x_m
//             out = relu(U + max_k V[m_k])   (relu monotone, U k-invariant)
// B=2, C=64, N=65536, K=16, OUT=64.
// r16 (50.6us): V int8, 64B row = 1 line = 1 request/edge; 4-lane/node
// dwordx4 gather (consecutive lanes share the line -> single request).
// r17 lesson: strided line-sharing + 32B nt stores + tiny VGPR = disaster.
// r18: ONE change vs r16 -- per-WAVE output tiles; block barrier #2 ->
// per-wave s_waitcnt lgkmcnt(0). Waves independent after idx stage: store
// tails overlap other waves' gathers. U-loads issued before gather loop.

using u32 = unsigned int;
using u16 = unsigned short;
using u8 = unsigned char;
typedef short short8 __attribute__((ext_vector_type(8)));
typedef float f32x4 __attribute__((ext_vector_type(4)));
typedef int i32x4 __attribute__((ext_vector_type(4)));
typedef u32 u32x4 __attribute__((ext_vector_type(4)));

#define NN 65536
#define VSCL 15.875f        // 127/8
#define VDEQ 0.0629921260f  // 8/127

static __device__ __forceinline__ u16 bf16r(float a) {
  u32 u = __builtin_bit_cast(u32, a);
  return (u16)((u + 0x7fffu + ((u >> 16) & 1u)) >> 16);  // RNE
}
static __device__ __forceinline__ u32 pack_bf16(float a, float b) {
  return (u32)bf16r(a) | ((u32)bf16r(b) << 16);
}
static __device__ __forceinline__ float bflo(u32 x) {
  return __builtin_bit_cast(float, x << 16);
}
static __device__ __forceinline__ float bfhi(u32 x) {
  return __builtin_bit_cast(float, x & 0xffff0000u);
}

// ---- kernel 0: Wcat[128][64] bf16: rows 0..63 = (W1-W2), 64..127 = W2 ----
__global__ __launch_bounds__(256) void prep_w(const float* __restrict__ W,
                                              u32* __restrict__ Wcat) {
  int id = blockIdx.x * 256 + threadIdx.x;  // 0..4095 (grid=16)
  int o = id >> 5, c2 = id & 31;
  float f0, f1;
  if (o < 64) {
    f0 = W[o * 128 + 2 * c2]     - W[o * 128 + 64 + 2 * c2];
    f1 = W[o * 128 + 2 * c2 + 1] - W[o * 128 + 64 + 2 * c2 + 1];
  } else {
    int om = o - 64;
    f0 = W[om * 128 + 64 + 2 * c2];
    f1 = W[om * 128 + 64 + 2 * c2 + 1];
  }
  Wcat[id] = pack_bf16(f0, f1);
}

// ---- kernel 1: U (bf16 128B rows), V8 (u8 64B rows) via MFMA GEMM ----
// (byte-identical to r16)
__global__ __launch_bounds__(256, 6) void k1(const float* __restrict__ x,
                                             const float* __restrict__ bias,
                                             const u32* __restrict__ Wcat,
                                             u32* __restrict__ Up,
                                             u32* __restrict__ V8p) {
  __shared__ __align__(16) char smem[26880];  // Wb(18432)+Xa(8448); TR(12800)
  u32* Wb = (u32*)smem;            // [128][36] u32  (row = 72 bf16, padded)
  u32* Xa = (u32*)(smem + 18432);  // [64][33] u32   (row = 66 bf16, padded)

  int t = threadIdx.x;
  int l = t & 63;   // lane
  int w = t >> 6;   // wave 0..3
  int b = blockIdx.x >> 10;
  int n0 = (blockIdx.x & 1023) << 6;

  // stage Wcat -> LDS (padded rows, conflict-free b128 reads later)
#pragma unroll
  for (int i = 0; i < 16; ++i) {
    int id = i * 256 + t;  // o = id>>5, c2 = id&31
    Wb[(id >> 5) * 36 + (id & 31)] = Wcat[id];
  }
  // stage x tile -> LDS bf16 pairs: Xa[node][ch], coalesced 256B reads
#pragma unroll
  for (int r = 0; r < 8; ++r) {
    int c2 = r * 4 + w;
    size_t base = ((size_t)(b * 64 + 2 * c2)) * NN + n0 + l;
    Xa[l * 33 + c2] = pack_bf16(x[base], x[base + NN]);
  }
  __syncthreads();

  f32x4 acc[8];
#pragma unroll
  for (int f = 0; f < 8; ++f) acc[f] = {0.f, 0.f, 0.f, 0.f};

  // wave w owns nodes 16w..16w+15 (C rows), all 128 outs (8 col-frags)
#pragma unroll
  for (int kb = 0; kb < 2; ++kb) {  // K = 64 = 2 x 32
    int ar = (16 * w + (l & 15)) * 33 + kb * 16 + 4 * (l >> 4);
    i32x4 av = {(int)Xa[ar], (int)Xa[ar + 1], (int)Xa[ar + 2], (int)Xa[ar + 3]};
    short8 a = __builtin_bit_cast(short8, av);
#pragma unroll
    for (int f = 0; f < 8; ++f) {
      i32x4 bv = *(const i32x4*)(Wb + (16 * f + (l & 15)) * 36 + kb * 16 + 4 * (l >> 4));
      short8 bb = __builtin_bit_cast(short8, bv);
      acc[f] = __builtin_amdgcn_mfma_f32_16x16x32_bf16(a, bb, acc[f], 0, 0, 0);
    }
  }

  float bs[4];
#pragma unroll
  for (int f = 0; f < 4; ++f) bs[f] = bias[16 * f + (l & 15)];

  __syncthreads();  // all waves done with Wb/Xa before TR reuse
  u16* TRU16 = (u16*)smem;            // [64 nodes][66 u16]: U row (64 bf16 + pad)
  u8* TRV8 = (u8*)(smem + 8448);      // [64 nodes][68 u8]:  V row (64 u8 + pad)
#pragma unroll
  for (int f = 0; f < 4; ++f) {
#pragma unroll
    for (int r = 0; r < 4; ++r) {
      int node = 16 * w + 4 * (l >> 4) + r;  // D row = (lane>>4)*4 + reg
      int o = 16 * f + (l & 15);             // D col = lane&15
      float uval = acc[f][r] + bs[f];        // Wcat rows 0..63 already (W1-W2)
      float vval = acc[f + 4][r];
      TRU16[node * 66 + o] = bf16r(uval);
      float q = fminf(fmaxf(vval * VSCL, -127.f), 127.f);
      TRV8[node * 68 + o] = (u8)((int)rintf(q) + 128);
    }
  }
  __syncthreads();

  // coalesced writeback: U 2048 u32 (8 iters), V8 1024 u32 (4 iters)
  u32* TRU32 = (u32*)smem;
  u32* TRV32 = (u32*)(smem + 8448);
#pragma unroll
  for (int i = 0; i < 8; ++i) {
    int id = i * 256 + t;  // node = id>>5, c = id&31
    int node = id >> 5, c = id & 31;
    Up[((size_t)b * NN + n0 + node) * 32 + c] = TRU32[node * 33 + c];
  }
#pragma unroll
  for (int i = 0; i < 4; ++i) {
    int id = i * 256 + t;  // node = id>>4, c = id&15
    int node = id >> 4, c = id & 15;
    V8p[((size_t)b * NN + n0 + node) * 16 + c] = TRV32[node * 17 + c];
  }
}

// ---- kernel 2: gather + max + relu; per-WAVE output tiles, one barrier ----
// slot = bx&7 (XCD): b = slot&1, quad = slot>>1; per-XCD table = 4.0MB.
// 4 lanes/node x dwordx4 = 64B row = 1 line/edge (consecutive-lane sharing).
__global__ __launch_bounds__(256, 6) void k2(const int* __restrict__ eidx,
                                             const u32* __restrict__ Up,
                                             const u32* __restrict__ V8p,
                                             float* __restrict__ out) {
  __shared__ __align__(16) int eixT[16 * 65];        // [e][node] idx
  __shared__ __align__(16) float wtile[4 * 1092];    // per-wave [64 ch][17]

  int t = threadIdx.x;
  int bx = blockIdx.x;
  int slot = bx & 7;
  int b = slot & 1;
  int quad = slot >> 1;
  int n0 = ((bx >> 3) + (quad << 8)) << 6;

  // stage + transpose this tile's 1024 indices (nt: don't evict V8 from L2)
  {
    i32x4 v = __builtin_nontemporal_load(
        (const i32x4*)(eidx + ((size_t)b * NN + n0) * 16) + t);
    int node = t >> 2, e0 = (t & 3) * 4;
    eixT[(e0 + 0) * 65 + node] = v.x;
    eixT[(e0 + 1) * 65 + node] = v.y;
    eixT[(e0 + 2) * 65 + node] = v.z;
    eixT[(e0 + 3) * 65 + node] = v.w;
  }
  __syncthreads();  // the ONLY block-wide barrier

  int l = t & 63, w = t >> 6;
  int nl = l >> 2;               // node-local 0..15
  int node = w * 16 + nl;
  int qq = l & 3;                // 16B quarter of the 64B row

  // U load issued EARLY (independent of gathers; drains under them)
  size_t ub = ((size_t)b * NN + n0 + node) * 32 + qq * 8;
  u32x4 uv0 = __builtin_nontemporal_load((const u32x4*)(Up + ub));
  u32x4 uv1 = __builtin_nontemporal_load((const u32x4*)(Up + ub + 4));

  const u32* Vb = V8p + ((size_t)b * NN) * 16 + qq * 4;
  float mx[16];  // biased-byte domain
#pragma unroll
  for (int i = 0; i < 16; ++i) mx[i] = 0.f;

#pragma unroll
  for (int hb = 0; hb < 4; ++hb) {
    u32x4 vr[4];
#pragma unroll
    for (int e = 0; e < 4; ++e) {
      int id = eixT[(hb * 4 + e) * 65 + node];  // LDS broadcast (4-lane group)
      vr[e] = *(const u32x4*)(Vb + (size_t)id * 16);  // 64B row: 1 line, L2-hot
    }
#pragma unroll
    for (int e = 0; e < 4; ++e) {
#pragma unroll
      for (int d = 0; d < 4; ++d) {
        u32 dw = vr[e][d];
        mx[4 * d + 0] = fmaxf(mx[4 * d + 0], (float)(dw & 0xffu));
        mx[4 * d + 1] = fmaxf(mx[4 * d + 1], (float)((dw >> 8) & 0xffu));
        mx[4 * d + 2] = fmaxf(mx[4 * d + 2], (float)((dw >> 16) & 0xffu));
        mx[4 * d + 3] = fmaxf(mx[4 * d + 3], (float)((dw >> 24) & 0xffu));
      }
    }
  }

  // write THIS WAVE's tile region: [o][nl] padded 17
  float* wt = wtile + w * 1092;
#pragma unroll
  for (int cc = 0; cc < 8; ++cc) {
    u32 uw = cc < 4 ? uv0[cc] : uv1[cc - 4];
    int o = qq * 16 + 2 * cc;
    wt[o * 17 + nl] = fmaxf(bflo(uw) + (mx[2 * cc] - 128.f) * VDEQ, 0.f);
    wt[(o + 1) * 17 + nl] = fmaxf(bfhi(uw) + (mx[2 * cc + 1] - 128.f) * VDEQ, 0.f);
  }

  // per-wave fence: all this wave's ds_writes done before its ds_reads
  asm volatile("s_waitcnt lgkmcnt(0)" ::: "memory");
  __builtin_amdgcn_sched_barrier(0);

  // per-wave coalesced output: 4 channels x 16 nodes (4x64B segs) per iter
  int oo = l >> 4;     // 0..3
  int nl2 = l & 15;
#pragma unroll
  for (int r = 0; r < 16; ++r) {
    int o = r * 4 + oo;
    __builtin_nontemporal_store(
        wt[o * 17 + nl2],
        out + ((size_t)(b * 64 + o)) * NN + n0 + w * 16 + nl2);
  }
}

extern "C" void kernel_launch(void* const* d_in, const int* in_sizes, int n_in,
                              void* d_out, int out_size, void* d_ws, size_t ws_size,
                              hipStream_t stream) {
  const float* x = (const float*)d_in[0];
  const int* eidx = (const int*)d_in[1];
  const float* W = (const float*)d_in[2];
  const float* bias = (const float*)d_in[3];

  // ws: U (16 MB, 2 x N x 32 u32) | V8 (8 MB, 2 x N x 16 u32) | Wcat (16 KB)
  u32* Up = (u32*)d_ws;
  u32* V8p = Up + (size_t)2 * NN * 32;
  u32* Wcat = (u32*)((char*)d_ws + (size_t)24 * 1024 * 1024);

  prep_w<<<16, 256, 0, stream>>>(W, Wcat);
  k1<<<2 * 1024, 256, 0, stream>>>(x, bias, Wcat, Up, V8p);
  k2<<<2 * 1024, 256, 0, stream>>>(eidx, Up, V8p, (float*)d_out);
}

// Round 19
// 50.556 us; speedup vs baseline: 1.3883x; 1.0835x over previous
//
#include <hip/hip_runtime.h>

// GraphConv2d (EdgeConv): out[b,o,n] = max_k relu( W·[x_n, x_m-x_n] + b )
// Factorized: U[b,n,o] = (W1-W2)·x_n + b ; V[b,m,o] = W2·x_m
//             out = relu(U + max_k V[m_k])   (relu monotone, U k-invariant)
// B=2, C=64, N=65536, K=16, OUT=64.
// == r16 config (best: 50.6us) + 2 micro tweaks: U-loads hoisted above the
// gather loop; gather batch 4->8. Structure untouched (r17/r18 lesson: the
// r16 phase structure / lane geometry / store shape is a local optimum).
// V int8: 64B row = 1 L2 line = 1 request/edge (2M total). Per-XCD gather
// table 4.0MB via slot=bx&7 (b=slot&1, quad=slot>>1). L2 random-request
// service ~6-8 req/cy/XCD (r8/r9/r16) -> k2 ~28us is near that rate.

using u32 = unsigned int;
using u16 = unsigned short;
using u8 = unsigned char;
typedef short short8 __attribute__((ext_vector_type(8)));
typedef float f32x4 __attribute__((ext_vector_type(4)));
typedef int i32x4 __attribute__((ext_vector_type(4)));
typedef u32 u32x4 __attribute__((ext_vector_type(4)));

#define NN 65536
#define VSCL 15.875f        // 127/8
#define VDEQ 0.0629921260f  // 8/127

static __device__ __forceinline__ u16 bf16r(float a) {
  u32 u = __builtin_bit_cast(u32, a);
  return (u16)((u + 0x7fffu + ((u >> 16) & 1u)) >> 16);  // RNE
}
static __device__ __forceinline__ u32 pack_bf16(float a, float b) {
  return (u32)bf16r(a) | ((u32)bf16r(b) << 16);
}
static __device__ __forceinline__ float bflo(u32 x) {
  return __builtin_bit_cast(float, x << 16);
}
static __device__ __forceinline__ float bfhi(u32 x) {
  return __builtin_bit_cast(float, x & 0xffff0000u);
}

// ---- kernel 0: Wcat[128][64] bf16: rows 0..63 = (W1-W2), 64..127 = W2 ----
__global__ __launch_bounds__(256) void prep_w(const float* __restrict__ W,
                                              u32* __restrict__ Wcat) {
  int id = blockIdx.x * 256 + threadIdx.x;  // 0..4095 (grid=16)
  int o = id >> 5, c2 = id & 31;
  float f0, f1;
  if (o < 64) {
    f0 = W[o * 128 + 2 * c2]     - W[o * 128 + 64 + 2 * c2];
    f1 = W[o * 128 + 2 * c2 + 1] - W[o * 128 + 64 + 2 * c2 + 1];
  } else {
    int om = o - 64;
    f0 = W[om * 128 + 64 + 2 * c2];
    f1 = W[om * 128 + 64 + 2 * c2 + 1];
  }
  Wcat[id] = pack_bf16(f0, f1);
}

// ---- kernel 1: U (bf16 128B rows), V8 (u8 64B rows) via MFMA GEMM ----
// (byte-identical to r16)
__global__ __launch_bounds__(256, 6) void k1(const float* __restrict__ x,
                                             const float* __restrict__ bias,
                                             const u32* __restrict__ Wcat,
                                             u32* __restrict__ Up,
                                             u32* __restrict__ V8p) {
  __shared__ __align__(16) char smem[26880];  // Wb(18432)+Xa(8448); TR(12800)
  u32* Wb = (u32*)smem;            // [128][36] u32  (row = 72 bf16, padded)
  u32* Xa = (u32*)(smem + 18432);  // [64][33] u32   (row = 66 bf16, padded)

  int t = threadIdx.x;
  int l = t & 63;   // lane
  int w = t >> 6;   // wave 0..3
  int b = blockIdx.x >> 10;
  int n0 = (blockIdx.x & 1023) << 6;

  // stage Wcat -> LDS (padded rows, conflict-free b128 reads later)
#pragma unroll
  for (int i = 0; i < 16; ++i) {
    int id = i * 256 + t;  // o = id>>5, c2 = id&31
    Wb[(id >> 5) * 36 + (id & 31)] = Wcat[id];
  }
  // stage x tile -> LDS bf16 pairs: Xa[node][ch], coalesced 256B reads
#pragma unroll
  for (int r = 0; r < 8; ++r) {
    int c2 = r * 4 + w;
    size_t base = ((size_t)(b * 64 + 2 * c2)) * NN + n0 + l;
    Xa[l * 33 + c2] = pack_bf16(x[base], x[base + NN]);
  }
  __syncthreads();

  f32x4 acc[8];
#pragma unroll
  for (int f = 0; f < 8; ++f) acc[f] = {0.f, 0.f, 0.f, 0.f};

  // wave w owns nodes 16w..16w+15 (C rows), all 128 outs (8 col-frags)
#pragma unroll
  for (int kb = 0; kb < 2; ++kb) {  // K = 64 = 2 x 32
    int ar = (16 * w + (l & 15)) * 33 + kb * 16 + 4 * (l >> 4);
    i32x4 av = {(int)Xa[ar], (int)Xa[ar + 1], (int)Xa[ar + 2], (int)Xa[ar + 3]};
    short8 a = __builtin_bit_cast(short8, av);
#pragma unroll
    for (int f = 0; f < 8; ++f) {
      i32x4 bv = *(const i32x4*)(Wb + (16 * f + (l & 15)) * 36 + kb * 16 + 4 * (l >> 4));
      short8 bb = __builtin_bit_cast(short8, bv);
      acc[f] = __builtin_amdgcn_mfma_f32_16x16x32_bf16(a, bb, acc[f], 0, 0, 0);
    }
  }

  float bs[4];
#pragma unroll
  for (int f = 0; f < 4; ++f) bs[f] = bias[16 * f + (l & 15)];

  __syncthreads();  // all waves done with Wb/Xa before TR reuse
  u16* TRU16 = (u16*)smem;            // [64 nodes][66 u16]: U row (64 bf16 + pad)
  u8* TRV8 = (u8*)(smem + 8448);      // [64 nodes][68 u8]:  V row (64 u8 + pad)
#pragma unroll
  for (int f = 0; f < 4; ++f) {
#pragma unroll
    for (int r = 0; r < 4; ++r) {
      int node = 16 * w + 4 * (l >> 4) + r;  // D row = (lane>>4)*4 + reg
      int o = 16 * f + (l & 15);             // D col = lane&15
      float uval = acc[f][r] + bs[f];        // Wcat rows 0..63 already (W1-W2)
      float vval = acc[f + 4][r];
      TRU16[node * 66 + o] = bf16r(uval);
      float q = fminf(fmaxf(vval * VSCL, -127.f), 127.f);
      TRV8[node * 68 + o] = (u8)((int)rintf(q) + 128);
    }
  }
  __syncthreads();

  // coalesced writeback: U 2048 u32 (8 iters), V8 1024 u32 (4 iters)
  u32* TRU32 = (u32*)smem;
  u32* TRV32 = (u32*)(smem + 8448);
#pragma unroll
  for (int i = 0; i < 8; ++i) {
    int id = i * 256 + t;  // node = id>>5, c = id&31
    int node = id >> 5, c = id & 31;
    Up[((size_t)b * NN + n0 + node) * 32 + c] = TRU32[node * 33 + c];
  }
#pragma unroll
  for (int i = 0; i < 4; ++i) {
    int id = i * 256 + t;  // node = id>>4, c = id&15
    int node = id >> 4, c = id & 15;
    V8p[((size_t)b * NN + n0 + node) * 16 + c] = TRV32[node * 17 + c];
  }
}

// ---- kernel 2: gather + max + relu (r16 structure) ----
// slot = bx&7 (XCD): b = slot&1, quad = slot>>1; per-XCD table = 4.0MB.
// 4 lanes/node x dwordx4 = 64B row = 1 line/edge; block-wide tile + 2
// barriers (r17/r18: any restructure of this loses).
__global__ __launch_bounds__(256, 6) void k2(const int* __restrict__ eidx,
                                             const u32* __restrict__ Up,
                                             const u32* __restrict__ V8p,
                                             float* __restrict__ out) {
  __shared__ __align__(16) int eixT[16 * 65];    // [e][node] idx, transposed
  __shared__ __align__(16) float tile[64 * 65];  // [o][node] padded

  int t = threadIdx.x;
  int bx = blockIdx.x;
  int slot = bx & 7;
  int b = slot & 1;
  int quad = slot >> 1;
  int n0 = (((bx >> 3) + (quad << 8))) << 6;

  // stage + transpose this tile's 1024 indices (nt: don't evict V8 from L2)
  {
    i32x4 v = __builtin_nontemporal_load(
        (const i32x4*)(eidx + ((size_t)b * NN + n0) * 16) + t);
    int node = t >> 2, e0 = (t & 3) * 4;
    eixT[(e0 + 0) * 65 + node] = v.x;
    eixT[(e0 + 1) * 65 + node] = v.y;
    eixT[(e0 + 2) * 65 + node] = v.z;
    eixT[(e0 + 3) * 65 + node] = v.w;
  }
  __syncthreads();

  int l = t & 63, w = t >> 6;
  int node = w * 16 + (l >> 2);  // 4 lanes per node
  int qq = l & 3;                // which 16B quarter of the 64B row

  // U-loads hoisted: independent of gathers, drain under the gather loop
  size_t ub = ((size_t)b * NN + n0 + node) * 32 + qq * 8;
  u32x4 uv0 = __builtin_nontemporal_load((const u32x4*)(Up + ub));
  u32x4 uv1 = __builtin_nontemporal_load((const u32x4*)(Up + ub + 4));

  const u32* Vb = V8p + ((size_t)b * NN) * 16 + qq * 4;
  float mx[16];  // biased-byte domain (bytes in [1,255])
#pragma unroll
  for (int i = 0; i < 16; ++i) mx[i] = 0.f;

#pragma unroll
  for (int hb = 0; hb < 2; ++hb) {
    u32x4 vr[8];
#pragma unroll
    for (int e = 0; e < 8; ++e) {
      int id = eixT[(hb * 8 + e) * 65 + node];  // LDS broadcast (4-lane group)
      vr[e] = *(const u32x4*)(Vb + (size_t)id * 16);  // 64B row: 1 line, L2-hot
    }
#pragma unroll
    for (int e = 0; e < 8; ++e) {
#pragma unroll
      for (int d = 0; d < 4; ++d) {
        u32 dw = vr[e][d];
        mx[4 * d + 0] = fmaxf(mx[4 * d + 0], (float)(dw & 0xffu));
        mx[4 * d + 1] = fmaxf(mx[4 * d + 1], (float)((dw >> 8) & 0xffu));
        mx[4 * d + 2] = fmaxf(mx[4 * d + 2], (float)((dw >> 16) & 0xffu));
        mx[4 * d + 3] = fmaxf(mx[4 * d + 3], (float)((dw >> 24) & 0xffu));
      }
    }
  }

#pragma unroll
  for (int cc = 0; cc < 8; ++cc) {
    u32 uw = cc < 4 ? uv0[cc] : uv1[cc - 4];
    int o = qq * 16 + 2 * cc;
    tile[o * 65 + node] =
        fmaxf(bflo(uw) + (mx[2 * cc] - 128.f) * VDEQ, 0.f);
    tile[(o + 1) * 65 + node] =
        fmaxf(bfhi(uw) + (mx[2 * cc + 1] - 128.f) * VDEQ, 0.f);
  }
  __syncthreads();

  // coalesced output: all 64 channels x 64 nodes
#pragma unroll
  for (int r = 0; r < 16; ++r) {
    int o = r * 4 + w;
    __builtin_nontemporal_store(
        tile[o * 65 + l],
        out + ((size_t)(b * 64 + o)) * NN + n0 + l);
  }
}

extern "C" void kernel_launch(void* const* d_in, const int* in_sizes, int n_in,
                              void* d_out, int out_size, void* d_ws, size_t ws_size,
                              hipStream_t stream) {
  const float* x = (const float*)d_in[0];
  const int* eidx = (const int*)d_in[1];
  const float* W = (const float*)d_in[2];
  const float* bias = (const float*)d_in[3];

  // ws: U (16 MB, 2 x N x 32 u32) | V8 (8 MB, 2 x N x 16 u32) | Wcat (16 KB)
  u32* Up = (u32*)d_ws;
  u32* V8p = Up + (size_t)2 * NN * 32;
  u32* Wcat = (u32*)((char*)d_ws + (size_t)24 * 1024 * 1024);

  prep_w<<<16, 256, 0, stream>>>(W, Wcat);
  k1<<<2 * 1024, 256, 0, stream>>>(x, bias, Wcat, Up, V8p);
  k2<<<2 * 1024, 256, 0, stream>>>(eidx, Up, V8p, (float*)d_out);
}